// Round 12
// baseline (757.855 us; speedup 1.0000x reference)
//
#include <hip/hip_runtime.h>

// Social-LSTM on MI355X. fp32 I/O. 14 launches total.
// Per frame ONE kernel k_step (500 blk x 512 thr, block owns 2 pedestrians):
//   gather te from Uin (R9-verified ILP-4 ballot-gather, 4 waves/ped)
//   -> ie -> gates matvec (W streamed from L2, shared across the 2 peds)
//   -> LSTM -> out-proj -> U rows for t+1 (verified pair-packed math).
// U double-buffered: the launch boundary is the only cross-block dependency.

#define TT    12
#define NN    1000
#define RNNW  128
#define OUTD  5
#define GROW  16000     // N*G floats per (t,n) grid row
#define UCW   1024
#define NCHK  63        // ceil(16000/256)

__device__ __forceinline__ float sigmf(float x) { return 1.f / (1.f + __expf(-x)); }

// ---- prep: WsT2p (pair-packed, R6 verified), WcT (k-major [256][512]),
// bsum[j], h/c init --------------------------------------------------------
__global__ void k_prep(const float* __restrict__ h0, const float* __restrict__ c0,
                       const float* __restrict__ W_soc,
                       const float* __restrict__ W_ih, const float* __restrict__ W_hh,
                       const float* __restrict__ b_ih, const float* __restrict__ b_hh,
                       float* __restrict__ h, float* __restrict__ c,
                       float* __restrict__ WsT2p, float* __restrict__ WcT,
                       float* __restrict__ bsum) {
    int i = blockIdx.x * 256 + threadIdx.x;
    if (i < 131072) {                       // WsT2p pair-packed k-major
        int e = i >> 11, gk = i & 2047, g = gk >> 7, k = gk & 127;
        int j = g * 64 + e;
        WsT2p[(k >> 1) * 2048 + j * 2 + (k & 1)] = W_soc[i];
    } else if (i < 196608) {                // W_ih [512][128] -> WcT[k][j]
        int i2 = i - 131072;
        int j = i2 >> 7, k = i2 & 127;
        WcT[k * 512 + j] = W_ih[i2];
    } else if (i < 262144) {                // W_hh -> WcT[128+k][j]
        int i3 = i - 196608;
        int j = i3 >> 7, k = i3 & 127;
        WcT[(128 + k) * 512 + j] = W_hh[i3];
    } else if (i < 262656) {                // bsum[j]
        int j = i - 262144;
        bsum[j] = b_ih[j] + b_hh[j];
    } else if (i < 262656 + NN * RNNW) {
        int i4 = i - 262656; h[i4] = h0[i4];
    } else if (i < 262656 + 2 * NN * RNNW) {
        int i5 = i - 262656 - NN * RNNW; c[i5] = c0[i5];
    }
}

// ---- U block-compute for 4 peds, h in LDS (R5/R6 verified) ---------------
__device__ __forceinline__ void compute_U(const float (*sH)[RNNW],
                                          const float* __restrict__ WsT2p,
                                          float* __restrict__ U, int n0, int tid) {
    const int jd = tid;
    float acc0[4] = {0.f, 0.f, 0.f, 0.f};
    float acc1[4] = {0.f, 0.f, 0.f, 0.f};
    for (int k = 0; k < RNNW; k += 4) {
        float4 a[4];
        #pragma unroll
        for (int p = 0; p < 4; ++p) a[p] = *(const float4*)(&sH[p][k]);
        const int r0 = (k >> 1), r1 = (k >> 1) + 1;
        float2 w00 = *(const float2*)(WsT2p + r0 * 2048 + jd * 2);
        float2 w01 = *(const float2*)(WsT2p + r0 * 2048 + (jd + 512) * 2);
        float2 w10 = *(const float2*)(WsT2p + r1 * 2048 + jd * 2);
        float2 w11 = *(const float2*)(WsT2p + r1 * 2048 + (jd + 512) * 2);
        #pragma unroll
        for (int p = 0; p < 4; ++p) {
            acc0[p] += a[p].x * w00.x + a[p].y * w00.y + a[p].z * w10.x + a[p].w * w10.y;
            acc1[p] += a[p].x * w01.x + a[p].y * w01.y + a[p].z * w11.x + a[p].w * w11.y;
        }
    }
    #pragma unroll
    for (int p = 0; p < 4; ++p) {
        U[(size_t)(n0 + p) * UCW + jd]       = acc0[p];
        U[(size_t)(n0 + p) * UCW + jd + 512] = acc1[p];
    }
}

// ---- U for frame 0 (R6 verified) -----------------------------------------
__global__ __launch_bounds__(512) void k_U0(const float* __restrict__ h,
                                            const float* __restrict__ WsT2p,
                                            float* __restrict__ U) {
    __shared__ float sH[4][RNNW];
    const int tid = threadIdx.x, n0 = blockIdx.x * 4;
    { int pl = tid >> 7, r = tid & 127; sH[pl][r] = h[(size_t)(n0 + pl) * RNNW + r]; }
    __syncthreads();
    compute_U(sH, WsT2p, U, n0, tid);
}

// ---- per-frame step: 500 blocks x 512 thr, 2 pedestrians per block -------
__global__ __launch_bounds__(512) void k_step(
    const unsigned int* __restrict__ grd, const float* __restrict__ x_in,
    const float* __restrict__ Uin, float* __restrict__ Uout,
    float* __restrict__ h, float* __restrict__ c,
    const float* __restrict__ WcT, const float* __restrict__ WsT2p,
    const float* __restrict__ W_in, const float* __restrict__ b_in,
    const float* __restrict__ b_soc, const float* __restrict__ bsum,
    const float* __restrict__ W_out, const float* __restrict__ b_out,
    float* __restrict__ out, int t, int doU)
{
    __shared__ float sAcc[8][64];
    __shared__ float sA[2][256];   // [ie(64) | te(64) | h(128)] per ped
    __shared__ float sG[2][512];
    __shared__ float sH[2][128];
    const int tid = threadIdx.x;
    const int lane = tid & 63, wv = tid >> 6;
    const int n0 = blockIdx.x * 2;

    // stage old h into sA[pl][128..255]
    if (tid < 256) {
        int pl = tid >> 7, r = tid & 127;
        sA[pl][128 + r] = h[(size_t)(n0 + pl) * RNNW + r];
    }

    // ---- gather: waves 0-3 ped0, waves 4-7 ped1; chunks cc = it*4+wq ----
    {
        const int pl = wv >> 2, wq = wv & 3;
        const unsigned int* gp = grd + (size_t)(t * NN + n0 + pl) * GROW;
        float ac0 = 0.f, ac1 = 0.f, ac2 = 0.f, ac3 = 0.f;
        for (int it = 0; it < 16; ++it) {
            int cc = it * 4 + wq;
            if (cc >= NCHK) break;
            int f0 = cc * 256 + lane * 4;
            uint4 v = {0u, 0u, 0u, 0u};
            if (f0 < GROW) v = *(const uint4*)(gp + f0);
            unsigned long long m0 = __ballot(v.x != 0u);
            unsigned long long m1 = __ballot(v.y != 0u);
            unsigned long long m2 = __ballot(v.z != 0u);
            unsigned long long m3 = __ballot(v.w != 0u);
            const int base = cc * 256;
            while (m0 | m1 | m2 | m3) {     // ILP-4 (R8/R9 verified)
                float u0 = 0.f, u1 = 0.f, u2 = 0.f, u3 = 0.f;
                if (m0) { int b = __builtin_ctzll(m0); m0 &= m0 - 1;
                          int f = base + b * 4 + 0;
                          u0 = Uin[(size_t)(f >> 4) * UCW + (f & 15) * 64 + lane]; }
                if (m1) { int b = __builtin_ctzll(m1); m1 &= m1 - 1;
                          int f = base + b * 4 + 1;
                          u1 = Uin[(size_t)(f >> 4) * UCW + (f & 15) * 64 + lane]; }
                if (m2) { int b = __builtin_ctzll(m2); m2 &= m2 - 1;
                          int f = base + b * 4 + 2;
                          u2 = Uin[(size_t)(f >> 4) * UCW + (f & 15) * 64 + lane]; }
                if (m3) { int b = __builtin_ctzll(m3); m3 &= m3 - 1;
                          int f = base + b * 4 + 3;
                          u3 = Uin[(size_t)(f >> 4) * UCW + (f & 15) * 64 + lane]; }
                ac0 += u0; ac1 += u1; ac2 += u2; ac3 += u3;   // +0.0f exact
            }
        }
        sAcc[wv][lane] = (ac0 + ac1) + (ac2 + ac3);
    }
    __syncthreads();
    // ---- te + ie --------------------------------------------------------
    if (tid < 128) {
        int pl = tid >> 6, e = tid & 63;
        float s = ((sAcc[pl * 4 + 0][e] + sAcc[pl * 4 + 1][e]) +
                   (sAcc[pl * 4 + 2][e] + sAcc[pl * 4 + 3][e]));
        float te = fmaxf(s + b_soc[e], 0.f);
        float x0 = x_in[(size_t)(t * NN + n0 + pl) * 2 + 0];
        float x1 = x_in[(size_t)(t * NN + n0 + pl) * 2 + 1];
        float ie = fmaxf(W_in[e * 2 + 0] * x0 + W_in[e * 2 + 1] * x1 + b_in[e], 0.f);
        sA[pl][e]      = ie;
        sA[pl][64 + e] = te;
    }
    __syncthreads();
    // ---- gates matvec: j = tid, both peds share the W stream ------------
    {
        float g0 = 0.f, g1 = 0.f;
        #pragma unroll 8
        for (int k = 0; k < 256; ++k) {
            float w = WcT[k * 512 + tid];
            g0 += sA[0][k] * w;
            g1 += sA[1][k] * w;
        }
        float bb = bsum[tid];
        sG[0][tid] = g0 + bb;
        sG[1][tid] = g1 + bb;
    }
    __syncthreads();
    // ---- LSTM -----------------------------------------------------------
    if (tid < 256) {
        int pl = tid >> 7, r = tid & 127;
        int n = n0 + pl;
        float gi = sG[pl][r], gf = sG[pl][128 + r];
        float gg = sG[pl][256 + r], go = sG[pl][384 + r];
        float cn = sigmf(gf) * c[(size_t)n * RNNW + r] + sigmf(gi) * tanhf(gg);
        float hn = sigmf(go) * tanhf(cn);
        c[(size_t)n * RNNW + r] = cn;
        h[(size_t)n * RNNW + r] = hn;
        sH[pl][r] = hn;
        if (t == TT - 1) {
            out[(size_t)TT * NN * OUTD + (size_t)n * RNNW + r] = hn;
            out[(size_t)TT * NN * OUTD + (size_t)NN * RNNW + (size_t)n * RNNW + r] = cn;
        }
    }
    __syncthreads();
    // ---- out-proj: 10 tasks (pl,d) x 32 lanes ---------------------------
    if (tid < 320) {
        int task = tid >> 5, l = tid & 31;
        int pl = task / OUTD, d = task - pl * OUTD;
        float pr = 0.f;
        #pragma unroll
        for (int q = 0; q < 4; ++q)
            pr += sH[pl][q * 32 + l] * W_out[d * RNNW + q * 32 + l];
        #pragma unroll
        for (int off = 16; off > 0; off >>= 1) pr += __shfl_down(pr, off, 32);
        if (l == 0)
            out[((size_t)t * NN + n0 + pl) * OUTD + d] = pr + b_out[d];
    }
    // ---- U rows for t+1 (pair-packed verified math, 2 peds) -------------
    if (doU) {
        const int jd = tid;
        float a00 = 0.f, a01 = 0.f, a10 = 0.f, a11 = 0.f;
        for (int k = 0; k < RNNW; k += 4) {
            float4 hA = *(const float4*)(&sH[0][k]);
            float4 hB = *(const float4*)(&sH[1][k]);
            const int r0 = (k >> 1), r1 = (k >> 1) + 1;
            float2 w00 = *(const float2*)(WsT2p + r0 * 2048 + jd * 2);
            float2 w01 = *(const float2*)(WsT2p + r0 * 2048 + (jd + 512) * 2);
            float2 w10 = *(const float2*)(WsT2p + r1 * 2048 + jd * 2);
            float2 w11 = *(const float2*)(WsT2p + r1 * 2048 + (jd + 512) * 2);
            a00 += hA.x * w00.x + hA.y * w00.y + hA.z * w10.x + hA.w * w10.y;
            a01 += hA.x * w01.x + hA.y * w01.y + hA.z * w11.x + hA.w * w11.y;
            a10 += hB.x * w00.x + hB.y * w00.y + hB.z * w10.x + hB.w * w10.y;
            a11 += hB.x * w01.x + hB.y * w01.y + hB.z * w11.x + hB.w * w11.y;
        }
        Uout[(size_t)(n0 + 0) * UCW + jd]       = a00;
        Uout[(size_t)(n0 + 0) * UCW + jd + 512] = a01;
        Uout[(size_t)(n0 + 1) * UCW + jd]       = a10;
        Uout[(size_t)(n0 + 1) * UCW + jd + 512] = a11;
    }
}

extern "C" void kernel_launch(void* const* d_in, const int* in_sizes, int n_in,
                              void* d_out, int out_size, void* d_ws, size_t ws_size,
                              hipStream_t stream) {
    const float* x_in       = (const float*)d_in[0];
    const unsigned int* grd = (const unsigned int*)d_in[1];
    const float* h0         = (const float*)d_in[2];
    const float* c0         = (const float*)d_in[3];
    const float* W_in       = (const float*)d_in[4];
    const float* b_in       = (const float*)d_in[5];
    const float* W_soc      = (const float*)d_in[6];
    const float* b_soc      = (const float*)d_in[7];
    const float* W_ih       = (const float*)d_in[8];
    const float* W_hh       = (const float*)d_in[9];
    const float* b_ih       = (const float*)d_in[10];
    const float* b_hh       = (const float*)d_in[11];
    const float* W_out      = (const float*)d_in[12];
    const float* b_out      = (const float*)d_in[13];
    float* out = (float*)d_out;

    float* h      = (float*)d_ws;                 // 128000
    float* c      = h + NN * RNNW;                // 128000
    float* U0b    = c + NN * RNNW;                // 1,024,000
    float* U1b    = U0b + (size_t)NN * UCW;       // 1,024,000
    float* WsT2p  = U1b + (size_t)NN * UCW;       // 131,072
    float* WcT    = WsT2p + 131072;               // 131,072
    float* bsum   = WcT + 131072;                 // 512

    hipLaunchKernelGGL(k_prep, dim3(2026), dim3(256), 0, stream,
                       h0, c0, W_soc, W_ih, W_hh, b_ih, b_hh, h, c, WsT2p, WcT, bsum);
    hipLaunchKernelGGL(k_U0, dim3(250), dim3(512), 0, stream, h, WsT2p, U0b);
    for (int t = 0; t < TT; ++t) {
        float* Uin  = (t & 1) ? U1b : U0b;
        float* Uout = (t & 1) ? U0b : U1b;
        hipLaunchKernelGGL(k_step, dim3(500), dim3(512), 0, stream,
                           grd, x_in, Uin, Uout, h, c, WcT, WsT2p,
                           W_in, b_in, b_soc, bsum, W_out, b_out,
                           out, t, (t < TT - 1) ? 1 : 0);
    }
}

// Round 13
// 676.469 us; speedup vs baseline: 1.1203x; 1.1203x over previous
//
#include <hip/hip_runtime.h>

// Social-LSTM on MI355X. fp32 I/O. 26 launches.
// Per frame: k_pool (1000 blk x 512, R9-verified ILP-4 ballot-gather -> A)
//            k_cell (250 blk x 512, R6-verified: pair-packed gates matvec +
//                    LSTM + out-proj + U' for t+1; final h,c folded at t=11).
// U[p][g*64+e] = sum_k h[p][k]*W_soc[e][g*128+k]; te = relu(sum_nz U + b_soc).

#define TT    12
#define NN    1000
#define RNNW  128
#define OUTD  5
#define GROW  16000     // N*G floats per (t,n) grid row
#define UCW   1024
#define NCHK  63        // ceil(16000/256)

__device__ __forceinline__ float sigmf(float x) { return 1.f / (1.f + __expf(-x)); }

// ---- prep: pair-packed weight repacks + h/c init (R6 verified) -----------
// WsT2p[(k>>1)*2048 + (g*64+e)*2 + (k&1)] = W_soc[e][g*128+k]
// WcT2p[(k>>1)*1024 + j*2 + (k&1)] = W_ih[j][k];  rows 64.. from W_hh
__global__ void k_prep(const float* __restrict__ h0, const float* __restrict__ c0,
                       const float* __restrict__ W_soc,
                       const float* __restrict__ W_ih, const float* __restrict__ W_hh,
                       float* __restrict__ h, float* __restrict__ c,
                       float* __restrict__ WsT2p, float* __restrict__ WcT2p) {
    int i = blockIdx.x * 256 + threadIdx.x;
    if (i < 131072) {
        int e = i >> 11, gk = i & 2047, g = gk >> 7, k = gk & 127;
        int j = g * 64 + e;
        WsT2p[(k >> 1) * 2048 + j * 2 + (k & 1)] = W_soc[i];
    } else if (i < 196608) {
        int i2 = i - 131072;               // W_ih [512][128]
        int j = i2 >> 7, k = i2 & 127;
        WcT2p[(k >> 1) * 1024 + j * 2 + (k & 1)] = W_ih[i2];
    } else if (i < 262144) {
        int i3 = i - 196608;               // W_hh [512][128]
        int j = i3 >> 7, k = i3 & 127;
        WcT2p[((k >> 1) + 64) * 1024 + j * 2 + (k & 1)] = W_hh[i3];
    } else if (i < 262144 + NN * RNNW) {
        int i4 = i - 262144; h[i4] = h0[i4];
    } else if (i < 262144 + 2 * NN * RNNW) {
        int i5 = i - 262144 - NN * RNNW; c[i5] = c0[i5];
    }
}

// ---- U block-compute for 4 pedestrians, h in LDS (R5/R6 verified) --------
__device__ __forceinline__ void compute_U(const float (*sH)[RNNW],
                                          const float* __restrict__ WsT2p,
                                          float* __restrict__ U, int n0, int tid) {
    const int jd = tid;
    float acc0[4] = {0.f, 0.f, 0.f, 0.f};
    float acc1[4] = {0.f, 0.f, 0.f, 0.f};
    for (int k = 0; k < RNNW; k += 4) {
        float4 a[4];
        #pragma unroll
        for (int p = 0; p < 4; ++p) a[p] = *(const float4*)(&sH[p][k]);
        const int r0 = (k >> 1), r1 = (k >> 1) + 1;
        float2 w00 = *(const float2*)(WsT2p + r0 * 2048 + jd * 2);
        float2 w01 = *(const float2*)(WsT2p + r0 * 2048 + (jd + 512) * 2);
        float2 w10 = *(const float2*)(WsT2p + r1 * 2048 + jd * 2);
        float2 w11 = *(const float2*)(WsT2p + r1 * 2048 + (jd + 512) * 2);
        #pragma unroll
        for (int p = 0; p < 4; ++p) {
            acc0[p] += a[p].x * w00.x + a[p].y * w00.y + a[p].z * w10.x + a[p].w * w10.y;
            acc1[p] += a[p].x * w01.x + a[p].y * w01.y + a[p].z * w11.x + a[p].w * w11.y;
        }
    }
    #pragma unroll
    for (int p = 0; p < 4; ++p) {
        U[(size_t)(n0 + p) * UCW + jd]       = acc0[p];
        U[(size_t)(n0 + p) * UCW + jd + 512] = acc1[p];
    }
}

// ---- U for frame 0 (R6 verified) -----------------------------------------
__global__ __launch_bounds__(512) void k_U0(const float* __restrict__ h,
                                            const float* __restrict__ WsT2p,
                                            float* __restrict__ U) {
    __shared__ float sH[4][RNNW];
    const int tid = threadIdx.x, n0 = blockIdx.x * 4;
    { int pl = tid >> 7, r = tid & 127; sH[pl][r] = h[(size_t)(n0 + pl) * RNNW + r]; }
    __syncthreads();
    compute_U(sH, WsT2p, U, n0, tid);
}

// ---- pool: 1000 blocks x 512 thr, ILP-4 gather (R9 verified) -------------
__global__ __launch_bounds__(512) void k_pool(const unsigned int* __restrict__ grd,
                                              const float* __restrict__ x_in,
                                              const float* __restrict__ U,
                                              const float* __restrict__ W_in,
                                              const float* __restrict__ b_in,
                                              const float* __restrict__ b_soc,
                                              float* __restrict__ A, int t) {
    const int n = blockIdx.x;
    const int tid = threadIdx.x;
    const int lane = tid & 63, wv = tid >> 6;            // 8 waves
    const unsigned int* gp = grd + ((size_t)t * NN + n) * (size_t)GROW;
    float ac0 = 0.f, ac1 = 0.f, ac2 = 0.f, ac3 = 0.f;
    for (int it = 0; it < 8; ++it) {
        int cc = it * 8 + wv;                            // wave-uniform chunk
        if (cc >= NCHK) break;
        int f0 = cc * 256 + lane * 4;
        uint4 v = {0u, 0u, 0u, 0u};
        if (f0 < GROW) v = *(const uint4*)(gp + f0);
        unsigned long long m0 = __ballot(v.x != 0u);
        unsigned long long m1 = __ballot(v.y != 0u);
        unsigned long long m2 = __ballot(v.z != 0u);
        unsigned long long m3 = __ballot(v.w != 0u);
        const int base = cc * 256;
        while (m0 | m1 | m2 | m3) {       // ILP-4: up to 4 loads in flight
            float u0 = 0.f, u1 = 0.f, u2 = 0.f, u3 = 0.f;
            if (m0) { int b = __builtin_ctzll(m0); m0 &= m0 - 1;
                      int f = base + b * 4 + 0;
                      u0 = U[(size_t)(f >> 4) * UCW + (f & 15) * 64 + lane]; }
            if (m1) { int b = __builtin_ctzll(m1); m1 &= m1 - 1;
                      int f = base + b * 4 + 1;
                      u1 = U[(size_t)(f >> 4) * UCW + (f & 15) * 64 + lane]; }
            if (m2) { int b = __builtin_ctzll(m2); m2 &= m2 - 1;
                      int f = base + b * 4 + 2;
                      u2 = U[(size_t)(f >> 4) * UCW + (f & 15) * 64 + lane]; }
            if (m3) { int b = __builtin_ctzll(m3); m3 &= m3 - 1;
                      int f = base + b * 4 + 3;
                      u3 = U[(size_t)(f >> 4) * UCW + (f & 15) * 64 + lane]; }
            ac0 += u0; ac1 += u1; ac2 += u2; ac3 += u3;  // +0.0f exact
        }
    }
    __shared__ float sAcc[8][64];
    sAcc[wv][lane] = (ac0 + ac1) + (ac2 + ac3);
    __syncthreads();
    if (tid < 64) {
        float s = 0.f;
        #pragma unroll
        for (int w = 0; w < 8; w++) s += sAcc[w][tid];
        float te = fmaxf(s + b_soc[tid], 0.f);
        float x0 = x_in[((size_t)t * NN + n) * 2 + 0];
        float x1 = x_in[((size_t)t * NN + n) * 2 + 1];
        float ie = fmaxf(W_in[tid * 2 + 0] * x0 + W_in[tid * 2 + 1] * x1 + b_in[tid], 0.f);
        A[(size_t)n * RNNW + tid]      = ie;
        A[(size_t)n * RNNW + 64 + tid] = te;
    }
}

// ---- cell: gates + LSTM + out-proj + U'(t+1). Block owns 4 peds. ---------
// (R6 verified; final h,c write folded at t==TT-1)
__global__ __launch_bounds__(512) void k_cell(const float* __restrict__ A,
                                              float* __restrict__ h, float* __restrict__ c,
                                              const float* __restrict__ WcT2p,
                                              const float* __restrict__ WsT2p,
                                              const float* __restrict__ b_ih,
                                              const float* __restrict__ b_hh,
                                              const float* __restrict__ W_out,
                                              const float* __restrict__ b_out,
                                              float* __restrict__ U,
                                              float* __restrict__ out, int t, int doU) {
    __shared__ float sA[4][RNNW], sH[4][RNNW], sC[4][RNNW];
    __shared__ float sG[4][512];
    __shared__ float sRed[4][2][OUTD];
    const int tid = threadIdx.x;
    const int lane = tid & 63;
    const int n0 = blockIdx.x * 4;
    {
        int pl = tid >> 7, r = tid & 127;
        sA[pl][r] = A[(size_t)(n0 + pl) * RNNW + r];
        sH[pl][r] = h[(size_t)(n0 + pl) * RNNW + r];
        sC[pl][r] = c[(size_t)(n0 + pl) * RNNW + r];
    }
    __syncthreads();
    {
        const int jh = tid & 255, ph = tid >> 8;
        float g00 = 0.f, g01 = 0.f, g10 = 0.f, g11 = 0.f;
        #pragma unroll 4
        for (int k = 0; k < 128; k += 4) {          // [ie|te] part
            float4 aA = *(const float4*)(&sA[2 * ph][k]);
            float4 aB = *(const float4*)(&sA[2 * ph + 1][k]);
            const int r0 = (k >> 1), r1 = (k >> 1) + 1;
            float2 w00 = *(const float2*)(WcT2p + r0 * 1024 + jh * 2);
            float2 w01 = *(const float2*)(WcT2p + r0 * 1024 + (jh + 256) * 2);
            float2 w10 = *(const float2*)(WcT2p + r1 * 1024 + jh * 2);
            float2 w11 = *(const float2*)(WcT2p + r1 * 1024 + (jh + 256) * 2);
            g00 += aA.x * w00.x + aA.y * w00.y + aA.z * w10.x + aA.w * w10.y;
            g01 += aA.x * w01.x + aA.y * w01.y + aA.z * w11.x + aA.w * w11.y;
            g10 += aB.x * w00.x + aB.y * w00.y + aB.z * w10.x + aB.w * w10.y;
            g11 += aB.x * w01.x + aB.y * w01.y + aB.z * w11.x + aB.w * w11.y;
        }
        #pragma unroll 4
        for (int k = 0; k < 128; k += 4) {          // h part (repack rows 64+)
            float4 aA = *(const float4*)(&sH[2 * ph][k]);
            float4 aB = *(const float4*)(&sH[2 * ph + 1][k]);
            const int r0 = 64 + (k >> 1), r1 = 64 + (k >> 1) + 1;
            float2 w00 = *(const float2*)(WcT2p + r0 * 1024 + jh * 2);
            float2 w01 = *(const float2*)(WcT2p + r0 * 1024 + (jh + 256) * 2);
            float2 w10 = *(const float2*)(WcT2p + r1 * 1024 + jh * 2);
            float2 w11 = *(const float2*)(WcT2p + r1 * 1024 + (jh + 256) * 2);
            g00 += aA.x * w00.x + aA.y * w00.y + aA.z * w10.x + aA.w * w10.y;
            g01 += aA.x * w01.x + aA.y * w01.y + aA.z * w11.x + aA.w * w11.y;
            g10 += aB.x * w00.x + aB.y * w00.y + aB.z * w10.x + aB.w * w10.y;
            g11 += aB.x * w01.x + aB.y * w01.y + aB.z * w11.x + aB.w * w11.y;
        }
        float bias0 = b_ih[jh] + b_hh[jh];
        float bias1 = b_ih[jh + 256] + b_hh[jh + 256];
        sG[2 * ph][jh]           = g00 + bias0;
        sG[2 * ph][jh + 256]     = g01 + bias1;
        sG[2 * ph + 1][jh]       = g10 + bias0;
        sG[2 * ph + 1][jh + 256] = g11 + bias1;
    }
    __syncthreads();
    {
        int pl = tid >> 7, r = tid & 127;
        float gi = sG[pl][r], gf = sG[pl][128 + r];
        float gg = sG[pl][256 + r], go = sG[pl][384 + r];
        float cn = sigmf(gf) * sC[pl][r] + sigmf(gi) * tanhf(gg);
        float hn = sigmf(go) * tanhf(cn);
        sC[pl][r] = cn;
        sH[pl][r] = hn;
        c[(size_t)(n0 + pl) * RNNW + r] = cn;
        h[(size_t)(n0 + pl) * RNNW + r] = hn;
        if (t == TT - 1) {   // folded final h,c tail of d_out
            out[(size_t)TT * NN * OUTD + (size_t)(n0 + pl) * RNNW + r] = hn;
            out[(size_t)TT * NN * OUTD + (size_t)NN * RNNW + (size_t)(n0 + pl) * RNNW + r] = cn;
        }
    }
    __syncthreads();
    {
        int pl = tid >> 7, p128 = tid & 127, wh = (tid >> 6) & 1;
        float v = sH[pl][p128];
        #pragma unroll
        for (int d = 0; d < OUTD; ++d) {
            float pr = v * W_out[d * RNNW + p128];
            #pragma unroll
            for (int off = 32; off > 0; off >>= 1) pr += __shfl_down(pr, off);
            if (lane == 0) sRed[pl][wh][d] = pr;
        }
    }
    __syncthreads();
    if (tid < 4 * OUTD) {
        int pl = tid / OUTD, d = tid % OUTD;
        out[((size_t)t * NN + n0 + pl) * OUTD + d] =
            sRed[pl][0][d] + sRed[pl][1][d] + b_out[d];
    }
    if (doU) compute_U(sH, WsT2p, U, n0, tid);
}

extern "C" void kernel_launch(void* const* d_in, const int* in_sizes, int n_in,
                              void* d_out, int out_size, void* d_ws, size_t ws_size,
                              hipStream_t stream) {
    const float* x_in       = (const float*)d_in[0];
    const unsigned int* grd = (const unsigned int*)d_in[1];
    const float* h0         = (const float*)d_in[2];
    const float* c0         = (const float*)d_in[3];
    const float* W_in       = (const float*)d_in[4];
    const float* b_in       = (const float*)d_in[5];
    const float* W_soc      = (const float*)d_in[6];
    const float* b_soc      = (const float*)d_in[7];
    const float* W_ih       = (const float*)d_in[8];
    const float* W_hh       = (const float*)d_in[9];
    const float* b_ih       = (const float*)d_in[10];
    const float* b_hh       = (const float*)d_in[11];
    const float* W_out      = (const float*)d_in[12];
    const float* b_out      = (const float*)d_in[13];
    float* out = (float*)d_out;

    float* h      = (float*)d_ws;                 // 128000
    float* c      = h + NN * RNNW;                // 128000
    float* U      = c + NN * RNNW;                // 1,024,000
    float* A      = U + (size_t)NN * UCW;         // 128,000
    float* WsT2p  = A + (size_t)NN * RNNW;        // 131,072
    float* WcT2p  = WsT2p + 131072;               // 131,072   (~6.1 MB)

    hipLaunchKernelGGL(k_prep, dim3(2024), dim3(256), 0, stream,
                       h0, c0, W_soc, W_ih, W_hh, h, c, WsT2p, WcT2p);
    hipLaunchKernelGGL(k_U0, dim3(250), dim3(512), 0, stream, h, WsT2p, U);
    for (int t = 0; t < TT; ++t) {
        hipLaunchKernelGGL(k_pool, dim3(NN), dim3(512), 0, stream,
                           grd, x_in, U, W_in, b_in, b_soc, A, t);
        hipLaunchKernelGGL(k_cell, dim3(250), dim3(512), 0, stream,
                           A, h, c, WcT2p, WsT2p, b_ih, b_hh, W_out, b_out,
                           U, out, t, (t < TT - 1) ? 1 : 0);
    }
}